// Round 1
// baseline (467.408 us; speedup 1.0000x reference)
//
#include <hip/hip_runtime.h>

#define BN 8192
#define DK 128

typedef __attribute__((ext_vector_type(8))) __bf16 bf16x8;
typedef __attribute__((ext_vector_type(4))) float float4v;

__device__ inline unsigned short f2bf(float f) {
  union { float f; unsigned u; } v;
  v.f = f;
  unsigned r = v.u + 0x7FFFu + ((v.u >> 16) & 1u);
  return (unsigned short)(r >> 16);
}

__device__ inline void async_copy16(const void* g, void* l) {
  __builtin_amdgcn_global_load_lds(
      (const __attribute__((address_space(1))) void*)g,
      (__attribute__((address_space(3))) void*)l, 16, 0, 0);
}

// Kernel 1: per-row L2 norms (fp32) + fp32->bf16 pack of A and B.
// One wave per row; 16384 waves total (A rows then B rows).
__global__ __launch_bounds__(256) void prep_kernel(
    const float* __restrict__ fa, const float* __restrict__ fb,
    unsigned short* __restrict__ abf, unsigned short* __restrict__ bbf,
    float* __restrict__ na, float* __restrict__ nb) {
  const int wave = threadIdx.x >> 6, lane = threadIdx.x & 63;
  const int w = blockIdx.x * 4 + wave;
  const int mat = w >> 13;            // 0 = A, 1 = B
  const int row = w & (BN - 1);
  const float* src = mat ? fb : fa;
  unsigned short* dst = mat ? bbf : abf;
  float* nrm = mat ? nb : na;
  const float2 v = ((const float2*)src)[row * 64 + lane];
  float s = v.x * v.x + v.y * v.y;
#pragma unroll
  for (int m = 32; m >= 1; m >>= 1) s += __shfl_xor(s, m, 64);
  ushort2 h;
  h.x = f2bf(v.x);
  h.y = f2bf(v.y);
  ((ushort2*)dst)[row * 64 + lane] = h;
  if (lane == 0) nrm[row] = sqrtf(s);
}

// Kernel 2: 128x128 tile of cos = (A_bf16 @ B_bf16^T) / max(na*nb, eps).
// Whole K=128 fits in one LDS stage (32 KB A + 32 KB B). 4 waves, each 64x64.
// Epilogue: write cos (nontemporal), accumulate per-row sum(exp(cos-1)),
// masked sum(cos), masked count via 16-lane reduce + atomics.
__global__ __launch_bounds__(256, 2) void gemm_kernel(
    const unsigned short* __restrict__ abf, const unsigned short* __restrict__ bbf,
    const float* __restrict__ na, const float* __restrict__ nb,
    const int* __restrict__ lab,
    float* __restrict__ out,            // out[0]=loss, out+1 = cos[8192][8192]
    float* __restrict__ lrow, float* __restrict__ srow, float* __restrict__ crow) {
  __shared__ alignas(16) unsigned short As[128 * 128];
  __shared__ alignas(16) unsigned short Bs[128 * 128];
  __shared__ int labr[128], labc[128];

  const int tid = threadIdx.x;
  const int wave = tid >> 6, lane = tid & 63;
  const int quad = lane >> 4, lcol = lane & 15;
  const int bx = blockIdx.x, by = blockIdx.y;

  if (tid < 128) labr[tid] = lab[by * 128 + tid];
  else           labc[tid - 128] = lab[bx * 128 + (tid - 128)];

  // Stage A and B tiles: each a contiguous 32 KB chunk of the bf16 matrices.
  const char* gA = (const char*)(abf + (size_t)by * 128 * 128);
  const char* gB = (const char*)(bbf + (size_t)bx * 128 * 128);
  char* lA = (char*)As;
  char* lB = (char*)Bs;
#pragma unroll
  for (int i = 0; i < 8; ++i) {
    const int chunk = i * 256 + wave * 64 + lane;  // lane-ordered contiguous
    async_copy16(gA + (size_t)chunk * 16, lA + (size_t)chunk * 16);
    async_copy16(gB + (size_t)chunk * 16, lB + (size_t)chunk * 16);
  }
  __syncthreads();

  const int m0 = (wave >> 1) * 64;   // wave's local row base
  const int n0 = (wave & 1) * 64;    // wave's local col base

  float4v acc[4][4];
#pragma unroll
  for (int i = 0; i < 4; ++i)
#pragma unroll
    for (int j = 0; j < 4; ++j) acc[i][j] = float4v{0.f, 0.f, 0.f, 0.f};

#pragma unroll
  for (int kb = 0; kb < 4; ++kb) {
    bf16x8 af[4], bfr[4];
#pragma unroll
    for (int i = 0; i < 4; ++i) {
      af[i]  = *(const bf16x8*)(&As[(m0 + i * 16 + lcol) * 128 + kb * 32 + quad * 8]);
      bfr[i] = *(const bf16x8*)(&Bs[(n0 + i * 16 + lcol) * 128 + kb * 32 + quad * 8]);
    }
#pragma unroll
    for (int i = 0; i < 4; ++i)
#pragma unroll
      for (int j = 0; j < 4; ++j)
        acc[i][j] = __builtin_amdgcn_mfma_f32_16x16x32_bf16(af[i], bfr[j], acc[i][j], 0, 0, 0);
  }

  // Epilogue. C/D layout: col = lane&15, row = quad*4 + reg.
#pragma unroll
  for (int i = 0; i < 4; ++i) {
    int rl[4], labrv[4];
    float nav[4], accE[4], accS[4], accC[4];
#pragma unroll
    for (int r = 0; r < 4; ++r) {
      rl[r] = m0 + i * 16 + quad * 4 + r;
      labrv[r] = labr[rl[r]];
      nav[r] = na[by * 128 + rl[r]];
      accE[r] = 0.f; accS[r] = 0.f; accC[r] = 0.f;
    }
#pragma unroll
    for (int j = 0; j < 4; ++j) {
      const int cl = n0 + j * 16 + lcol;
      const int gc = bx * 128 + cl;
      const float nbv = nb[gc];
      const int labcv = labc[cl];
#pragma unroll
      for (int r = 0; r < 4; ++r) {
        const float d = fmaxf(nav[r] * nbv, 1e-8f);
        const float cv = acc[i][j][r] * __builtin_amdgcn_rcpf(d);
        const size_t grow = (size_t)(by * 128 + rl[r]);
        __builtin_nontemporal_store(cv, &out[1 + (grow << 13) + (size_t)gc]);
        accE[r] += __expf(cv - 1.0f);
        if (labrv[r] == labcv) { accS[r] += cv; accC[r] += 1.0f; }
      }
    }
#pragma unroll
    for (int r = 0; r < 4; ++r) {
#pragma unroll
      for (int m = 1; m <= 8; m <<= 1) {
        accE[r] += __shfl_xor(accE[r], m, 64);
        accS[r] += __shfl_xor(accS[r], m, 64);
        accC[r] += __shfl_xor(accC[r], m, 64);
      }
    }
    if (lcol == 0) {
#pragma unroll
      for (int r = 0; r < 4; ++r) {
        const int grow = by * 128 + rl[r];
        atomicAdd(&lrow[grow], accE[r]);
        atomicAdd(&srow[grow], accS[r]);
        atomicAdd(&crow[grow], accC[r]);
      }
    }
  }
}

// Kernel 3: loss = -sum_i [S_i - C_i*(1 + log l_i)] / B^2, single block.
__global__ __launch_bounds__(1024) void loss_kernel(
    const float* __restrict__ lrow, const float* __restrict__ srow,
    const float* __restrict__ crow, float* __restrict__ out) {
  __shared__ float red[1024];
  float p = 0.f;
  for (int r = threadIdx.x; r < BN; r += 1024)
    p += srow[r] - crow[r] * (1.0f + __logf(lrow[r]));
  red[threadIdx.x] = p;
  __syncthreads();
  for (int s = 512; s >= 1; s >>= 1) {
    if (threadIdx.x < s) red[threadIdx.x] += red[threadIdx.x + s];
    __syncthreads();
  }
  if (threadIdx.x == 0) out[0] = -red[0] / 67108864.0f;  // B*B = 2^26 exact
}

extern "C" void kernel_launch(void* const* d_in, const int* in_sizes, int n_in,
                              void* d_out, int out_size, void* d_ws, size_t ws_size,
                              hipStream_t stream) {
  const int* lab = (const int*)d_in[0];
  const float* fa = (const float*)d_in[1];
  const float* fb = (const float*)d_in[2];
  float* out = (float*)d_out;

  char* ws = (char*)d_ws;
  unsigned short* abf = (unsigned short*)ws;                          // 2 MB
  unsigned short* bbf = (unsigned short*)(ws + (2u << 20));           // 2 MB
  float* na   = (float*)(ws + (4u << 20));                            // 32 KB
  float* nb   = (float*)(ws + (4u << 20) + 32768);                    // 32 KB
  float* lrow = (float*)(ws + (4u << 20) + 2 * 32768);                // 32 KB
  float* srow = (float*)(ws + (4u << 20) + 3 * 32768);                // 32 KB
  float* crow = (float*)(ws + (4u << 20) + 4 * 32768);                // 32 KB

  hipMemsetAsync(ws + (4u << 20) + 2 * 32768, 0, 3 * 32768, stream);

  prep_kernel<<<4096, 256, 0, stream>>>(fa, fb, abf, bbf, na, nb);
  gemm_kernel<<<dim3(64, 64), 256, 0, stream>>>(abf, bbf, na, nb, lab, out,
                                                lrow, srow, crow);
  loss_kernel<<<1, 1024, 0, stream>>>(lrow, srow, crow, out);
}

// Round 2
// 467.167 us; speedup vs baseline: 1.0005x; 1.0005x over previous
//
#include <hip/hip_runtime.h>

#define BN 8192

typedef __attribute__((ext_vector_type(8))) __bf16 bf16x8;
typedef __attribute__((ext_vector_type(8))) unsigned short ushort8;
typedef __attribute__((ext_vector_type(4))) float float4v;

__device__ inline unsigned short f2bf(float f) {
  union { float f; unsigned u; } v;
  v.f = f;
  unsigned r = v.u + 0x7FFFu + ((v.u >> 16) & 1u);
  return (unsigned short)(r >> 16);
}

// Kernel 1: per-row reciprocal L2 norms (fp32) + fp32->bf16 pack of A and B.
__global__ __launch_bounds__(256) void prep_kernel(
    const float* __restrict__ fa, const float* __restrict__ fb,
    unsigned short* __restrict__ abf, unsigned short* __restrict__ bbf,
    float* __restrict__ rna, float* __restrict__ rnb) {
  const int wave = threadIdx.x >> 6, lane = threadIdx.x & 63;
  const int w = blockIdx.x * 4 + wave;
  const int mat = w >> 13;            // 0 = A, 1 = B
  const int row = w & (BN - 1);
  const float* src = mat ? fb : fa;
  unsigned short* dst = mat ? bbf : abf;
  float* nrm = mat ? rnb : rna;
  const float2 v = ((const float2*)src)[row * 64 + lane];
  float s = v.x * v.x + v.y * v.y;
#pragma unroll
  for (int m = 32; m >= 1; m >>= 1) s += __shfl_xor(s, m, 64);
  ushort2 h;
  h.x = f2bf(v.x);
  h.y = f2bf(v.y);
  ((ushort2*)dst)[row * 64 + lane] = h;
  if (lane == 0) nrm[row] = 1.0f / sqrtf(s);  // norms ~sqrt(128); eps clamp vacuous
}

// Kernel 2: 128x128 tile of cos = (A @ B^T) * rna * rnb, bf16 MFMA.
// LDS: 64KB staging (XOR-swizzled for bank-ideal b128 fragment reads),
// reused as 64KB float Cs tile for the epilogue transpose so global writes
// are row-contiguous (L2 merges the +4B-misaligned stream).
__global__ __launch_bounds__(256, 2) void gemm_kernel(
    const unsigned short* __restrict__ abf, const unsigned short* __restrict__ bbf,
    const float* __restrict__ rna, const float* __restrict__ rnb,
    const int* __restrict__ lab,
    float* __restrict__ out,            // out[0]=loss, out+1 = cos[8192][8192]
    float* __restrict__ lrow, float* __restrict__ srow) {
  __shared__ alignas(16) unsigned char smem[65536];
  __shared__ int labr[128], labc[128];
  ushort8* As = (ushort8*)smem;                 // 2048 16B chunks (32 KB)
  ushort8* Bs = (ushort8*)(smem + 32768);       // 2048 16B chunks (32 KB)
  float* Cs = (float*)smem;                     // 128x128 fp32 (64 KB), reuse

  const int tid = threadIdx.x;
  const int wave = tid >> 6, lane = tid & 63;
  const int quad = lane >> 4, lcol = lane & 15;
  const int bx = blockIdx.x, by = blockIdx.y;

  if (tid < 128) labr[tid] = lab[by * 128 + tid];
  else           labc[tid - 128] = lab[bx * 128 + (tid - 128)];

  // --- Stage A/B tiles with chunk XOR swizzle: chunk (r,c) -> r*16 + (c^(r&15))
  const ushort8* gA = (const ushort8*)(abf + (size_t)by * 128 * 128);
  const ushort8* gB = (const ushort8*)(bbf + (size_t)bx * 128 * 128);
#pragma unroll
  for (int it = 0; it < 8; ++it) {
    const int L = it * 256 + tid;        // linear chunk 0..2047
    const int r = L >> 4, c = L & 15;
    const int pos = r * 16 + (c ^ (r & 15));
    const ushort8 va = gA[L];
    const ushort8 vb = gB[L];
    As[pos] = va;
    Bs[pos] = vb;
  }
  __syncthreads();

  const int m0 = (wave >> 1) * 64;   // wave's local row base
  const int n0 = (wave & 1) * 64;    // wave's local col base

  float4v acc[4][4];
#pragma unroll
  for (int i = 0; i < 4; ++i)
#pragma unroll
    for (int j = 0; j < 4; ++j) acc[i][j] = float4v{0.f, 0.f, 0.f, 0.f};

#pragma unroll
  for (int kb = 0; kb < 4; ++kb) {
    bf16x8 af[4], bfr[4];
    const int csw = (kb * 4 + quad) ^ lcol;   // row&15 == lcol for both A and B
#pragma unroll
    for (int i = 0; i < 4; ++i) {
      af[i]  = *(const bf16x8*)&As[(m0 + i * 16 + lcol) * 16 + csw];
      bfr[i] = *(const bf16x8*)&Bs[(n0 + i * 16 + lcol) * 16 + csw];
    }
#pragma unroll
    for (int i = 0; i < 4; ++i)
#pragma unroll
      for (int j = 0; j < 4; ++j)
        acc[i][j] = __builtin_amdgcn_mfma_f32_16x16x32_bf16(af[i], bfr[j], acc[i][j], 0, 0, 0);
  }

  __syncthreads();   // all waves done reading As/Bs; smem becomes Cs

  // --- Epilogue: cv -> Cs (rotated cols for bank-ideal writes) + E/S sums.
  // C/D layout: col = lane&15 (+j*16), row = quad*4 + reg (+i*16).
  float rnbv[4];
  int labcv[4];
#pragma unroll
  for (int j = 0; j < 4; ++j) {
    const int cl = n0 + j * 16 + lcol;
    rnbv[j] = rnb[bx * 128 + cl];
    labcv[j] = labc[cl];
  }
#pragma unroll
  for (int i = 0; i < 4; ++i) {
    int rowl[4], labrv[4];
    float rnav[4], accE[4], accS[4];
#pragma unroll
    for (int r = 0; r < 4; ++r) {
      rowl[r] = m0 + i * 16 + quad * 4 + r;
      labrv[r] = labr[rowl[r]];
      rnav[r] = rna[by * 128 + rowl[r]];
      accE[r] = 0.f; accS[r] = 0.f;
    }
#pragma unroll
    for (int j = 0; j < 4; ++j) {
      const int col = n0 + j * 16 + lcol;
#pragma unroll
      for (int r = 0; r < 4; ++r) {
        const float cv = acc[i][j][r] * rnav[r] * rnbv[j];
        Cs[rowl[r] * 128 + ((col + quad * 8) & 127)] = cv;
        accE[r] += __expf(cv - 1.0f);
        if (labrv[r] == labcv[j]) accS[r] += cv;
      }
    }
#pragma unroll
    for (int r = 0; r < 4; ++r) {
#pragma unroll
      for (int m = 1; m <= 8; m <<= 1) {
        accE[r] += __shfl_xor(accE[r], m, 64);
        accS[r] += __shfl_xor(accS[r], m, 64);
      }
    }
    if (lcol == 0) {
#pragma unroll
      for (int r = 0; r < 4; ++r) {
        const int grow = by * 128 + rowl[r];
        atomicAdd(&lrow[grow], accE[r]);
        atomicAdd(&srow[grow], accS[r]);
      }
    }
  }
  __syncthreads();   // Cs tile complete

  // --- Row-contiguous writeback: wave handles 32 rows, 2x64 dwords per row.
  const int r0 = wave * 32;
  const size_t gbase = 1 + ((size_t)(by * 128 + r0) << 13) + (size_t)bx * 128;
#pragma unroll 4
  for (int rr = 0; rr < 32; ++rr) {
    const int row = r0 + rr;
    const int s = ((row >> 2) & 3) * 8;   // matches writer's quad*8 rotation
    const float v0 = Cs[row * 128 + ((lane + s) & 127)];
    const float v1 = Cs[row * 128 + ((lane + 64 + s) & 127)];
    out[gbase + (size_t)rr * 8192 + lane] = v0;
    out[gbase + (size_t)rr * 8192 + 64 + lane] = v1;
  }
}

// Kernel 3: loss = -sum_i [S_i - C_i*(1 + log l_i)] / B^2, single block.
// C_i = hist[label_i] (exact count, no need to accumulate in gemm).
__global__ __launch_bounds__(1024) void loss_kernel(
    const int* __restrict__ lab, const float* __restrict__ lrow,
    const float* __restrict__ srow, float* __restrict__ out) {
  __shared__ int hist[2048];
  __shared__ float red[1024];
  for (int i = threadIdx.x; i < 2048; i += 1024) hist[i] = 0;
  __syncthreads();
  for (int i = threadIdx.x; i < BN; i += 1024) atomicAdd(&hist[lab[i]], 1);
  __syncthreads();
  float p = 0.f;
  for (int i = threadIdx.x; i < BN; i += 1024)
    p += srow[i] - (float)hist[lab[i]] * (1.0f + __logf(lrow[i]));
  red[threadIdx.x] = p;
  __syncthreads();
  for (int s = 512; s >= 1; s >>= 1) {
    if (threadIdx.x < s) red[threadIdx.x] += red[threadIdx.x + s];
    __syncthreads();
  }
  if (threadIdx.x == 0) out[0] = -red[0] / 67108864.0f;  // B*B = 2^26 exact
}

extern "C" void kernel_launch(void* const* d_in, const int* in_sizes, int n_in,
                              void* d_out, int out_size, void* d_ws, size_t ws_size,
                              hipStream_t stream) {
  const int* lab = (const int*)d_in[0];
  const float* fa = (const float*)d_in[1];
  const float* fb = (const float*)d_in[2];
  float* out = (float*)d_out;

  char* ws = (char*)d_ws;
  unsigned short* abf = (unsigned short*)ws;                          // 2 MB
  unsigned short* bbf = (unsigned short*)(ws + (2u << 20));           // 2 MB
  float* rna  = (float*)(ws + (4u << 20));                            // 32 KB
  float* rnb  = (float*)(ws + (4u << 20) + 32768);                    // 32 KB
  float* lrow = (float*)(ws + (4u << 20) + 2 * 32768);                // 32 KB
  float* srow = (float*)(ws + (4u << 20) + 3 * 32768);                // 32 KB

  hipMemsetAsync(ws + (4u << 20) + 2 * 32768, 0, 2 * 32768, stream);

  prep_kernel<<<4096, 256, 0, stream>>>(fa, fb, abf, bbf, rna, rnb);
  gemm_kernel<<<dim3(64, 64), 256, 0, stream>>>(abf, bbf, rna, rnb, lab, out,
                                                lrow, srow);
  loss_kernel<<<1, 1024, 0, stream>>>(lab, lrow, srow, out);
}